// Round 8
// baseline (729.050 us; speedup 1.0000x reference)
//
#include <hip/hip_runtime.h>
#include <hip/hip_bf16.h>
#include <hip/hip_cooperative_groups.h>

namespace cg = cooperative_groups;

// Renderer vertex-normals rev17. Math FROZEN from rev8 (passing, absmax = 1 bf16 ulp):
//   cross: c_i = fmaf(a_p, b_q, -pinned(a_q*b_p))  (uniform LHS fusion)
//   norms: (x*x + y*y) + z*z, sqrtf, fmaxf(n,1e-12f), IEEE '/'
//   vertex sum: c = 0..5 sequential per (v,batch) accumulator
// Rev17 = ONE cooperative kernel (pack -> grid.sync -> face -> grid.sync ->
//   vertex), same per-phase bodies as rev16 (packed 48-B interleaved tables,
//   quad-split lane mapping, XCD partitioning, nt streams).
//   Evidence: kernels sum to ~87 us but total is 163; ~32 us is launch-
//   boundary overhead (~8-10 us x boundaries) and ~44 us the harness's ws
//   fill. Fusing removes 2 boundaries AND lets face read the 3.15 MB ptsP
//   slice still dirty in its XCD's L2 from the pack phase (~25 MB FETCH
//   saved). Grid = 2048 blocks = 8/CU co-resident (__launch_bounds__(256,8),
//   <=64 VGPR); each phase grid-strides x4 preserving the %8 XCD mapping; no
//   cross-XCD dataflow so per-XCD L2 coherence + grid.sync suffices.
//   Face phase FPT=2 (FPT 2 vs 3 measured null; fits the VGPR cap).
//   Runtime fallback: if hipLaunchCooperativeKernel errors -> proven rev16
//   3-kernel path (identical math), then rev8 path on ws shortage.
// bs=32, V=65536, F=130050, C=6.

#define XCDS 8
#define BPX  4   // batches per XCD; fast path requires bs == XCDS*BPX == 32
#define FPT  3   // faces/thread in the NON-cooperative face kernel (F%3==0)

__device__ __forceinline__ float mulf_pin(float a, float b) {
  float t = a * b;
  asm("" : "+v"(t));   // pin: separately-rounded f32 product, cannot re-fuse
  return t;
}

__device__ __forceinline__ float3 cross_lhs(float ax, float ay, float az,
                                            float bx, float by, float bz) {
  float cx = __builtin_fmaf(ay, bz, -mulf_pin(az, by));
  float cy = __builtin_fmaf(az, bx, -mulf_pin(ax, bz));
  float cz = __builtin_fmaf(ax, by, -mulf_pin(ay, bx));
  return make_float3(cx, cy, cz);
}

// ---------------- phase bodies (shared by mega + split kernels) ------------

__device__ __forceinline__ void pack_body(
    const float* __restrict__ points, float* __restrict__ ptsP,
    int V, int xcd, int g) {
  int v  = g >> 2;
  int bl = g & 3;
  int b  = xcd * BPX + bl;
  const float* pb = points + (size_t)b * 3 * V;
  float x = __builtin_nontemporal_load(pb + v);
  float y = __builtin_nontemporal_load(pb + V + v);
  float z = __builtin_nontemporal_load(pb + 2 * V + v);
  float* e = ptsP + ((size_t)xcd * V + v) * 12 + 3 * bl;
  e[0] = x; e[1] = y; e[2] = z;
}

__device__ __forceinline__ void face1_body(
    const float* __restrict__ ptsP, const int* __restrict__ faces,
    float* __restrict__ fnP, int F, int V, int xcd, int f, int bl) {
  int i0 = __builtin_nontemporal_load(faces + 3 * f + 0);
  int i1 = __builtin_nontemporal_load(faces + 3 * f + 1);
  int i2 = __builtin_nontemporal_load(faces + 3 * f + 2);
  const float* P = ptsP + (size_t)xcd * V * 12 + 3 * bl;
  const float* e0 = P + (size_t)i0 * 12;
  const float* e1 = P + (size_t)i1 * 12;
  const float* e2 = P + (size_t)i2 * 12;
  float p0x = e0[0], p0y = e0[1], p0z = e0[2];
  float p1x = e1[0], p1y = e1[1], p1z = e1[2];
  float p2x = e2[0], p2y = e2[1], p2z = e2[2];
  float ax = p1x - p0x, ay = p1y - p0y, az = p1z - p0z;
  float bx = p2x - p0x, by = p2y - p0y, bz = p2z - p0z;
  float3 c = cross_lhs(ax, ay, az, bx, by, bz);
  float n = sqrtf((c.x * c.x + c.y * c.y) + c.z * c.z);
  float d = fmaxf(n, 1e-12f);
  float* o = fnP + (size_t)xcd * F * 12 + (size_t)f * 12 + 3 * bl;
  __builtin_nontemporal_store(c.x / d, o + 0);
  __builtin_nontemporal_store(c.y / d, o + 1);
  __builtin_nontemporal_store(c.z / d, o + 2);
}

__device__ __forceinline__ void vertex_body(
    const float* __restrict__ fnP, const int* __restrict__ vti,
    const float* __restrict__ vtw, float* __restrict__ out,
    int F, int V, int xcd, int g) {
  int v  = g >> 2;
  int bl = g & 3;

  int i0 = __builtin_nontemporal_load(vti + (size_t)v * 6 + 0);
  int i1 = __builtin_nontemporal_load(vti + (size_t)v * 6 + 1);
  int i2 = __builtin_nontemporal_load(vti + (size_t)v * 6 + 2);
  int i3 = __builtin_nontemporal_load(vti + (size_t)v * 6 + 3);
  int i4 = __builtin_nontemporal_load(vti + (size_t)v * 6 + 4);
  int i5 = __builtin_nontemporal_load(vti + (size_t)v * 6 + 5);
  float w0 = __builtin_nontemporal_load(vtw + (size_t)v * 6 + 0);
  float w1 = __builtin_nontemporal_load(vtw + (size_t)v * 6 + 1);
  float w2 = __builtin_nontemporal_load(vtw + (size_t)v * 6 + 2);
  float w3 = __builtin_nontemporal_load(vtw + (size_t)v * 6 + 3);
  float w4 = __builtin_nontemporal_load(vtw + (size_t)v * 6 + 4);
  float w5 = __builtin_nontemporal_load(vtw + (size_t)v * 6 + 5);

  const float* P = fnP + (size_t)xcd * F * 12 + 3 * bl;
  const float* e0 = P + (size_t)i0 * 12;
  const float* e1 = P + (size_t)i1 * 12;
  const float* e2 = P + (size_t)i2 * 12;
  const float* e3 = P + (size_t)i3 * 12;
  const float* e4 = P + (size_t)i4 * 12;
  const float* e5 = P + (size_t)i5 * 12;

  float n0x = e0[0], n0y = e0[1], n0z = e0[2];
  float n1x = e1[0], n1y = e1[1], n1z = e1[2];
  float n2x = e2[0], n2y = e2[1], n2z = e2[2];
  float n3x = e3[0], n3y = e3[1], n3z = e3[2];
  float n4x = e4[0], n4y = e4[1], n4z = e4[2];
  float n5x = e5[0], n5y = e5[1], n5z = e5[2];

  float sx = 0.f, sy = 0.f, sz = 0.f;   // frozen c = 0..5 order
  sx += n0x * w0; sy += n0y * w0; sz += n0z * w0;
  sx += n1x * w1; sy += n1y * w1; sz += n1z * w1;
  sx += n2x * w2; sy += n2y * w2; sz += n2z * w2;
  sx += n3x * w3; sy += n3y * w3; sz += n3z * w3;
  sx += n4x * w4; sy += n4y * w4; sz += n4z * w4;
  sx += n5x * w5; sy += n5y * w5; sz += n5z * w5;

  float n = sqrtf((sx * sx + sy * sy) + sz * sz);
  float d = fmaxf(n, 1e-12f);

  int b = xcd * BPX + bl;
  size_t o = ((size_t)b * V + v) * 3;
  __builtin_nontemporal_store(sx / d, out + o + 0);
  __builtin_nontemporal_store(sy / d, out + o + 1);
  __builtin_nontemporal_store(sz / d, out + o + 2);
}

// ---------------- Cooperative mega-kernel: pack|sync|face|sync|vertex ------
// Grid MUST be 2048 blocks x 256 threads (8 blocks/CU co-resident).
// Requires V == 65536 (grid-stride x4 covers V*BPX exactly).
__global__ __launch_bounds__(256, 8) void rend17_mega(
    const float* __restrict__ points, const int* __restrict__ faces,
    const int* __restrict__ vti, const float* __restrict__ vtw,
    float* __restrict__ out, float* __restrict__ ptsP,
    float* __restrict__ fnP, int F, int V, int Q2) {
  cg::grid_group grid = cg::this_grid();
  int xcd = blockIdx.x & (XCDS - 1);
  int s0  = blockIdx.x >> 3;            // 0..255
  int tid = threadIdx.x;

  // Phase 1: pack (V*BPX = 262144 threads/XCD = 1024 units; 4 strides)
#pragma unroll
  for (int k = 0; k < 4; ++k) {
    int g = ((s0 + (k << 8)) << 8) + tid;
    pack_body(points, ptsP, V, xcd, g);
  }
  grid.sync();

  // Phase 2: face, FPT=2 (Q2 = F/2 quads -> 2 faces per thread)
#pragma unroll
  for (int k = 0; k < 4; ++k) {
    int g  = ((s0 + (k << 8)) << 8) + tid;
    int q  = g >> 2;
    int bl = g & 3;
    if (q < Q2) {
      face1_body(ptsP, faces, fnP, F, V, xcd, q, bl);
      face1_body(ptsP, faces, fnP, F, V, xcd, q + Q2, bl);
    }
  }
  grid.sync();

  // Phase 3: vertex
#pragma unroll
  for (int k = 0; k < 4; ++k) {
    int g = ((s0 + (k << 8)) << 8) + tid;
    vertex_body(fnP, vti, vtw, out, F, V, xcd, g);
  }
}

// ---------------- Split kernels (rev16, proven fallback path) --------------
__global__ __launch_bounds__(256) void rend17_pack(
    const float* __restrict__ points, float* __restrict__ ptsP, int V) {
  int xcd = blockIdx.x % XCDS;
  int g   = (blockIdx.x / XCDS) * 256 + threadIdx.x;
  pack_body(points, ptsP, V, xcd, g);
}

__global__ __launch_bounds__(256) void rend17_face(
    const float* __restrict__ ptsP, const int* __restrict__ faces,
    float* __restrict__ fnP, int F, int V, int Q) {
  int xcd = blockIdx.x % XCDS;
  int g   = (blockIdx.x / XCDS) * 256 + threadIdx.x;
  int q   = g >> 2;
  int bl  = g & 3;
  if (q >= Q) return;
  face1_body(ptsP, faces, fnP, F, V, xcd, q, bl);
  face1_body(ptsP, faces, fnP, F, V, xcd, q + Q, bl);
  face1_body(ptsP, faces, fnP, F, V, xcd, q + 2 * Q, bl);
}

__global__ __launch_bounds__(256) void rend17_vertex(
    const float* __restrict__ fnP, const int* __restrict__ vti,
    const float* __restrict__ vtw, float* __restrict__ out, int F, int V) {
  int xcd = blockIdx.x % XCDS;
  int g   = (blockIdx.x / XCDS) * 256 + threadIdx.x;
  if ((g >> 2) >= V) return;
  vertex_body(fnP, vti, vtw, out, F, V, xcd, g);
}

// ================= Fallback path (rev8, proven): ===========================
__global__ __launch_bounds__(256) void rend17_face_fb(
    const float* __restrict__ points,
    const int*   __restrict__ faces,
    float4*      __restrict__ fnorm,
    int F, int V) {
  int f = blockIdx.x * blockDim.x + threadIdx.x;
  int b = blockIdx.y;
  if (f >= F) return;

  int i0 = faces[3 * f + 0];
  int i1 = faces[3 * f + 1];
  int i2 = faces[3 * f + 2];

  const float* pb = points + (size_t)b * 3 * V;
  float ax = pb[i1] - pb[i0], ay = pb[V + i1] - pb[V + i0], az = pb[2 * V + i1] - pb[2 * V + i0];
  float bx = pb[i2] - pb[i0], by = pb[V + i2] - pb[V + i0], bz = pb[2 * V + i2] - pb[2 * V + i0];

  float3 c = cross_lhs(ax, ay, az, bx, by, bz);

  float n = sqrtf((c.x * c.x + c.y * c.y) + c.z * c.z);
  float d = fmaxf(n, 1e-12f);

  fnorm[(size_t)b * F + f] = make_float4(c.x / d, c.y / d, c.z / d, 0.0f);
}

__global__ __launch_bounds__(256) void rend17_vertex_fb(
    const float4* __restrict__ fnorm,
    const int*    __restrict__ vti,
    const float*  __restrict__ vtw,
    float*        __restrict__ out,
    int F, int V) {
  int v = blockIdx.x * blockDim.x + threadIdx.x;
  int b = blockIdx.y;
  if (v >= V) return;

  const float4* fb = fnorm + (size_t)b * F;
  float sx = 0.f, sy = 0.f, sz = 0.f;
#pragma unroll
  for (int c = 0; c < 6; ++c) {
    int    idx = vti[v * 6 + c];
    float  w   = vtw[v * 6 + c];
    float4 nr  = fb[idx];
    sx += nr.x * w;
    sy += nr.y * w;
    sz += nr.z * w;
  }
  float n = sqrtf((sx * sx + sy * sy) + sz * sz);
  float d = fmaxf(n, 1e-12f);
  size_t o = ((size_t)b * V + v) * 3;
  out[o + 0] = sx / d;
  out[o + 1] = sy / d;
  out[o + 2] = sz / d;
}

extern "C" void kernel_launch(void* const* d_in, const int* in_sizes, int n_in,
                              void* d_out, int out_size, void* d_ws, size_t ws_size,
                              hipStream_t stream) {
  const float* points = (const float*)d_in[0];
  const int*   faces  = (const int*)d_in[1];
  const int*   vti    = (const int*)d_in[2];
  const float* vtw    = (const float*)d_in[3];
  float*       out    = (float*)d_out;

  const int F  = in_sizes[1] / 3;                       // 130050
  const int V  = in_sizes[2] / 6;                       // 65536
  const int bs = (int)(in_sizes[0] / (3 * (size_t)V));  // 32

  const size_t ptsP_bytes = (size_t)bs * V * 12;        // 25.2 MB (packed)
  const size_t fnP_bytes  = (size_t)bs * F * 12;        // 49.9 MB (packed)
  const size_t fn_bytes   = (size_t)bs * F * sizeof(float4);  // rev8 fallback

  const bool tables_ok = (ws_size >= ptsP_bytes + fnP_bytes) &&
                         (bs == XCDS * BPX);

  // ---- Preferred: single cooperative kernel (exact-shape requirements) ----
  if (tables_ok && V == 65536 && (F % 2 == 0)) {
    float* ptsP = (float*)d_ws;
    float* fnP  = (float*)((char*)d_ws + ptsP_bytes);
    int Fa = F, Va = V, Q2 = F / 2;
    void* kargs[] = {(void*)&points, (void*)&faces, (void*)&vti, (void*)&vtw,
                     (void*)&out, (void*)&ptsP, (void*)&fnP,
                     (void*)&Fa, (void*)&Va, (void*)&Q2};
    hipError_t e = hipLaunchCooperativeKernel(
        (const void*)rend17_mega, dim3(XCDS * 256), dim3(256), kargs, 0, stream);
    if (e == hipSuccess) return;
    (void)hipGetLastError();   // clear sticky error; fall through to split path
  }

  // ---- Proven rev16 split path ----
  if (tables_ok && ((V * BPX) % 256 == 0) && (F % FPT == 0)) {
    float* ptsP = (float*)d_ws;
    float* fnP  = (float*)((char*)d_ws + ptsP_bytes);
    const int Q   = F / FPT;
    const int ppb = (V * BPX) / 256;
    const int fqb = (Q * 4 + 255) / 256;
    const int vqb = (V * BPX) / 256;

    rend17_pack  <<<dim3(XCDS * ppb), dim3(256), 0, stream>>>(points, ptsP, V);
    rend17_face  <<<dim3(XCDS * fqb), dim3(256), 0, stream>>>(ptsP, faces, fnP, F, V, Q);
    rend17_vertex<<<dim3(XCDS * vqb), dim3(256), 0, stream>>>(fnP, vti, vtw, out, F, V);
  } else if (ws_size >= fn_bytes) {  // rev8 fallback
    float4* fnorm = (float4*)d_ws;
    rend17_face_fb<<<dim3((F + 255) / 256, bs), dim3(256), 0, stream>>>(
        points, faces, fnorm, F, V);
    rend17_vertex_fb<<<dim3((V + 255) / 256, bs), dim3(256), 0, stream>>>(
        fnorm, vti, vtw, out, F, V);
  }
}

// Round 9
// 161.961 us; speedup vs baseline: 4.5014x; 4.5014x over previous
//
#include <hip/hip_runtime.h>
#include <hip/hip_bf16.h>

// Renderer vertex-normals rev18. Math FROZEN from rev8 (passing, absmax = 1 bf16 ulp):
//   cross: c_i = fmaf(a_p, b_q, -pinned(a_q*b_p))  (uniform LHS fusion)
//   norms: (x*x + y*y) + z*z, sqrtf, fmaxf(n,1e-12f), IEEE '/'
//   vertex sum: c = 0..5 sequential per (v,batch) accumulator
// Rev18 = rev16 split path (coop mega REVERTED: rev17 = 662 us, VALU 2.3% —
//   grid.sync spin dominates; launch-boundary fusion is a dead end) with ONE
//   store-policy change:
//     fn stores in the face pass: nontemporal -> REGULAR (write-allocate).
//   Mechanism: vertex's persistent ~29 MB refetch (FETCH 103.6 vs ~75 MB
//   compulsory) exists because the 6.24 MB/XCD fn slice > 4 MB L2 AND nt
//   stores leave ZERO fn resident at vertex launch. Regular stores leave up
//   to ~4 MB/XCD dirty-resident -> warm-start hit band for vertex's random
//   gathers. The nt choice protected rev12's 4.19 MB ptsI slice; packed ptsP
//   (3.15 MB, rev16) fits L2 with headroom, so the protection is obsolete.
//   Store policy doesn't change values -> bit-identical output.
// Kept from rev16: packed 48-B interleaved tables, quad-split lane mapping,
//   XCD partitioning, FPT=3 face, VPT=1 vertex, nt streaming loads,
//   nt out stores, frozen FP order.
// bs=32, V=65536, F=130050, C=6.

#define XCDS 8
#define BPX  4   // batches per XCD; fast path requires bs == XCDS*BPX == 32
#define FPT  3   // faces per thread in the face pass (requires F % FPT == 0)

__device__ __forceinline__ float mulf_pin(float a, float b) {
  float t = a * b;
  asm("" : "+v"(t));   // pin: separately-rounded f32 product, cannot re-fuse
  return t;
}

__device__ __forceinline__ float3 cross_lhs(float ax, float ay, float az,
                                            float bx, float by, float bz) {
  float cx = __builtin_fmaf(ay, bz, -mulf_pin(az, by));
  float cy = __builtin_fmaf(az, bx, -mulf_pin(ax, bz));
  float cz = __builtin_fmaf(ax, by, -mulf_pin(ay, bx));
  return make_float3(cx, cy, cz);
}

// ---------------- Kernel A: packed batch-interleaved point pack ------------
// Thread g -> (v = g>>2, bl = g&3). 3 coalesced nt loads; 3 regular stores
// into the XCD's own 3.15 MB slice (stays dirty in L2 for kernel B).
__global__ __launch_bounds__(256) void rend18_pack(
    const float* __restrict__ points,   // (bs, 3, V)
    float*       __restrict__ ptsP,     // (XCDS, V, 12 floats)
    int V) {
  int xcd = blockIdx.x % XCDS;
  int g   = (blockIdx.x / XCDS) * 256 + threadIdx.x;
  int v   = g >> 2;
  int bl  = g & 3;
  int b   = xcd * BPX + bl;
  const float* pb = points + (size_t)b * 3 * V;
  float x = __builtin_nontemporal_load(pb + v);
  float y = __builtin_nontemporal_load(pb + V + v);
  float z = __builtin_nontemporal_load(pb + 2 * V + v);
  float* e = ptsP + ((size_t)xcd * V + v) * 12 + 3 * bl;
  e[0] = x; e[1] = y; e[2] = z;
}

// ---------------- Kernel B: face normals, quad-split, FPT=3, packed --------
// Thread (q, bl) handles f_k = q + k*Q (Q = F/3): 9 index loads, then 9
// independent quad-merged 48-B gathers, then three frozen compute+store
// sequences. fn stores REGULAR (write-allocate): leave the tail of fn
// dirty-resident in this XCD's L2 for the vertex pass.
__global__ __launch_bounds__(256) void rend18_face(
    const float* __restrict__ ptsP,     // (XCDS, V, 12 floats)
    const int*   __restrict__ faces,    // (F, 3)
    float*       __restrict__ fnP,      // (XCDS, F, 12 floats)
    int F, int V, int Q) {
  int xcd = blockIdx.x % XCDS;
  int g   = (blockIdx.x / XCDS) * 256 + threadIdx.x;
  int q   = g >> 2;
  int bl  = g & 3;
  if (q >= Q) return;

  int f0 = q;
  int f1 = q + Q;
  int f2 = q + 2 * Q;

  int a0 = __builtin_nontemporal_load(faces + 3 * f0 + 0);
  int a1 = __builtin_nontemporal_load(faces + 3 * f0 + 1);
  int a2 = __builtin_nontemporal_load(faces + 3 * f0 + 2);
  int b0 = __builtin_nontemporal_load(faces + 3 * f1 + 0);
  int b1 = __builtin_nontemporal_load(faces + 3 * f1 + 1);
  int b2 = __builtin_nontemporal_load(faces + 3 * f1 + 2);
  int c0 = __builtin_nontemporal_load(faces + 3 * f2 + 0);
  int c1 = __builtin_nontemporal_load(faces + 3 * f2 + 1);
  int c2 = __builtin_nontemporal_load(faces + 3 * f2 + 2);

  const float* P = ptsP + (size_t)xcd * V * 12 + 3 * bl;
  const float* ea0 = P + (size_t)a0 * 12;
  const float* ea1 = P + (size_t)a1 * 12;
  const float* ea2 = P + (size_t)a2 * 12;
  const float* eb0 = P + (size_t)b0 * 12;
  const float* eb1 = P + (size_t)b1 * 12;
  const float* eb2 = P + (size_t)b2 * 12;
  const float* ec0 = P + (size_t)c0 * 12;
  const float* ec1 = P + (size_t)c1 * 12;
  const float* ec2 = P + (size_t)c2 * 12;

  float a0x = ea0[0], a0y = ea0[1], a0z = ea0[2];
  float a1x = ea1[0], a1y = ea1[1], a1z = ea1[2];
  float a2x = ea2[0], a2y = ea2[1], a2z = ea2[2];
  float b0x = eb0[0], b0y = eb0[1], b0z = eb0[2];
  float b1x = eb1[0], b1y = eb1[1], b1z = eb1[2];
  float b2x = eb2[0], b2y = eb2[1], b2z = eb2[2];
  float c0x = ec0[0], c0y = ec0[1], c0z = ec0[2];
  float c1x = ec1[0], c1y = ec1[1], c1z = ec1[2];
  float c2x = ec2[0], c2y = ec2[1], c2z = ec2[2];

  float* O = fnP + (size_t)xcd * F * 12 + 3 * bl;
  {
    float ax = a1x - a0x, ay = a1y - a0y, az = a1z - a0z;
    float bx = a2x - a0x, by = a2y - a0y, bz = a2z - a0z;
    float3 c = cross_lhs(ax, ay, az, bx, by, bz);
    float n = sqrtf((c.x * c.x + c.y * c.y) + c.z * c.z);
    float d = fmaxf(n, 1e-12f);
    float* o = O + (size_t)f0 * 12;
    o[0] = c.x / d; o[1] = c.y / d; o[2] = c.z / d;
  }
  {
    float ax = b1x - b0x, ay = b1y - b0y, az = b1z - b0z;
    float bx = b2x - b0x, by = b2y - b0y, bz = b2z - b0z;
    float3 c = cross_lhs(ax, ay, az, bx, by, bz);
    float n = sqrtf((c.x * c.x + c.y * c.y) + c.z * c.z);
    float d = fmaxf(n, 1e-12f);
    float* o = O + (size_t)f1 * 12;
    o[0] = c.x / d; o[1] = c.y / d; o[2] = c.z / d;
  }
  {
    float ax = c1x - c0x, ay = c1y - c0y, az = c1z - c0z;
    float bx = c2x - c0x, by = c2y - c0y, bz = c2z - c0z;
    float3 c = cross_lhs(ax, ay, az, bx, by, bz);
    float n = sqrtf((c.x * c.x + c.y * c.y) + c.z * c.z);
    float d = fmaxf(n, 1e-12f);
    float* o = O + (size_t)f2 * 12;
    o[0] = c.x / d; o[1] = c.y / d; o[2] = c.z / d;
  }
}

// ---------------- Kernel C: vertex normals, quad-split, packed -------------
// Thread (v, bl): 6 nt table loads -> 6 independent quad-merged 48-B gathers
// (warm-start band from face's regular stores) -> frozen c=0..5 weighted sum
// -> normalize -> 3 nt stores.
__global__ __launch_bounds__(256) void rend18_vertex(
    const float* __restrict__ fnP,      // (XCDS, F, 12 floats)
    const int*   __restrict__ vti,      // (V, 6)
    const float* __restrict__ vtw,      // (V, 6)
    float*       __restrict__ out,      // (bs, V, 3)
    int F, int V) {
  int xcd = blockIdx.x % XCDS;
  int g   = (blockIdx.x / XCDS) * 256 + threadIdx.x;
  int v   = g >> 2;
  int bl  = g & 3;
  if (v >= V) return;

  int i0 = __builtin_nontemporal_load(vti + (size_t)v * 6 + 0);
  int i1 = __builtin_nontemporal_load(vti + (size_t)v * 6 + 1);
  int i2 = __builtin_nontemporal_load(vti + (size_t)v * 6 + 2);
  int i3 = __builtin_nontemporal_load(vti + (size_t)v * 6 + 3);
  int i4 = __builtin_nontemporal_load(vti + (size_t)v * 6 + 4);
  int i5 = __builtin_nontemporal_load(vti + (size_t)v * 6 + 5);
  float w0 = __builtin_nontemporal_load(vtw + (size_t)v * 6 + 0);
  float w1 = __builtin_nontemporal_load(vtw + (size_t)v * 6 + 1);
  float w2 = __builtin_nontemporal_load(vtw + (size_t)v * 6 + 2);
  float w3 = __builtin_nontemporal_load(vtw + (size_t)v * 6 + 3);
  float w4 = __builtin_nontemporal_load(vtw + (size_t)v * 6 + 4);
  float w5 = __builtin_nontemporal_load(vtw + (size_t)v * 6 + 5);

  const float* P = fnP + (size_t)xcd * F * 12 + 3 * bl;
  const float* e0 = P + (size_t)i0 * 12;
  const float* e1 = P + (size_t)i1 * 12;
  const float* e2 = P + (size_t)i2 * 12;
  const float* e3 = P + (size_t)i3 * 12;
  const float* e4 = P + (size_t)i4 * 12;
  const float* e5 = P + (size_t)i5 * 12;

  float n0x = e0[0], n0y = e0[1], n0z = e0[2];
  float n1x = e1[0], n1y = e1[1], n1z = e1[2];
  float n2x = e2[0], n2y = e2[1], n2z = e2[2];
  float n3x = e3[0], n3y = e3[1], n3z = e3[2];
  float n4x = e4[0], n4y = e4[1], n4z = e4[2];
  float n5x = e5[0], n5y = e5[1], n5z = e5[2];

  // Frozen c = 0..5 sequential accumulation.
  float sx = 0.f, sy = 0.f, sz = 0.f;
  sx += n0x * w0; sy += n0y * w0; sz += n0z * w0;
  sx += n1x * w1; sy += n1y * w1; sz += n1z * w1;
  sx += n2x * w2; sy += n2y * w2; sz += n2z * w2;
  sx += n3x * w3; sy += n3y * w3; sz += n3z * w3;
  sx += n4x * w4; sy += n4y * w4; sz += n4z * w4;
  sx += n5x * w5; sy += n5y * w5; sz += n5z * w5;

  float n = sqrtf((sx * sx + sy * sy) + sz * sz);
  float d = fmaxf(n, 1e-12f);

  int b = xcd * BPX + bl;
  size_t o = ((size_t)b * V + v) * 3;
  __builtin_nontemporal_store(sx / d, out + o + 0);
  __builtin_nontemporal_store(sy / d, out + o + 1);
  __builtin_nontemporal_store(sz / d, out + o + 2);
}

// ================= Fallback path (rev8, proven): ===========================
__global__ __launch_bounds__(256) void rend18_face_fb(
    const float* __restrict__ points,
    const int*   __restrict__ faces,
    float4*      __restrict__ fnorm,
    int F, int V) {
  int f = blockIdx.x * blockDim.x + threadIdx.x;
  int b = blockIdx.y;
  if (f >= F) return;

  int i0 = faces[3 * f + 0];
  int i1 = faces[3 * f + 1];
  int i2 = faces[3 * f + 2];

  const float* pb = points + (size_t)b * 3 * V;
  float ax = pb[i1] - pb[i0], ay = pb[V + i1] - pb[V + i0], az = pb[2 * V + i1] - pb[2 * V + i0];
  float bx = pb[i2] - pb[i0], by = pb[V + i2] - pb[V + i0], bz = pb[2 * V + i2] - pb[2 * V + i0];

  float3 c = cross_lhs(ax, ay, az, bx, by, bz);

  float n = sqrtf((c.x * c.x + c.y * c.y) + c.z * c.z);
  float d = fmaxf(n, 1e-12f);

  fnorm[(size_t)b * F + f] = make_float4(c.x / d, c.y / d, c.z / d, 0.0f);
}

__global__ __launch_bounds__(256) void rend18_vertex_fb(
    const float4* __restrict__ fnorm,
    const int*    __restrict__ vti,
    const float*  __restrict__ vtw,
    float*        __restrict__ out,
    int F, int V) {
  int v = blockIdx.x * blockDim.x + threadIdx.x;
  int b = blockIdx.y;
  if (v >= V) return;

  const float4* fb = fnorm + (size_t)b * F;
  float sx = 0.f, sy = 0.f, sz = 0.f;
#pragma unroll
  for (int c = 0; c < 6; ++c) {
    int    idx = vti[v * 6 + c];
    float  w   = vtw[v * 6 + c];
    float4 nr  = fb[idx];
    sx += nr.x * w;
    sy += nr.y * w;
    sz += nr.z * w;
  }
  float n = sqrtf((sx * sx + sy * sy) + sz * sz);
  float d = fmaxf(n, 1e-12f);
  size_t o = ((size_t)b * V + v) * 3;
  out[o + 0] = sx / d;
  out[o + 1] = sy / d;
  out[o + 2] = sz / d;
}

extern "C" void kernel_launch(void* const* d_in, const int* in_sizes, int n_in,
                              void* d_out, int out_size, void* d_ws, size_t ws_size,
                              hipStream_t stream) {
  const float* points = (const float*)d_in[0];
  const int*   faces  = (const int*)d_in[1];
  const int*   vti    = (const int*)d_in[2];
  const float* vtw    = (const float*)d_in[3];
  float*       out    = (float*)d_out;

  const int F  = in_sizes[1] / 3;                       // 130050
  const int V  = in_sizes[2] / 6;                       // 65536
  const int bs = (int)(in_sizes[0] / (3 * (size_t)V));  // 32

  const size_t ptsP_bytes = (size_t)bs * V * 12;        // 25.2 MB (packed)
  const size_t fnP_bytes  = (size_t)bs * F * 12;        // 49.9 MB (packed)
  const size_t fn_bytes   = (size_t)bs * F * sizeof(float4);  // fallback only

  const bool fast_ok = (ws_size >= ptsP_bytes + fnP_bytes) &&
                       (bs == XCDS * BPX) && ((V * BPX) % 256 == 0) &&
                       (F % FPT == 0);

  if (fast_ok) {
    float* ptsP = (float*)d_ws;
    float* fnP  = (float*)((char*)d_ws + ptsP_bytes);
    const int Q   = F / FPT;                        // 43350 face-triples
    const int ppb = (V * BPX) / 256;                // 1024 pack-blocks per XCD
    const int fqb = (Q * 4 + 255) / 256;            // 678 face-quad blocks per XCD
    const int vqb = (V * BPX) / 256;                // 1024 vertex-quad blocks per XCD

    rend18_pack  <<<dim3(XCDS * ppb), dim3(256), 0, stream>>>(points, ptsP, V);
    rend18_face  <<<dim3(XCDS * fqb), dim3(256), 0, stream>>>(ptsP, faces, fnP, F, V, Q);
    rend18_vertex<<<dim3(XCDS * vqb), dim3(256), 0, stream>>>(fnP, vti, vtw, out, F, V);
  } else if (ws_size >= fn_bytes) {  // rev8 fallback
    float4* fnorm = (float4*)d_ws;
    rend18_face_fb<<<dim3((F + 255) / 256, bs), dim3(256), 0, stream>>>(
        points, faces, fnorm, F, V);
    rend18_vertex_fb<<<dim3((V + 255) / 256, bs), dim3(256), 0, stream>>>(
        fnorm, vti, vtw, out, F, V);
  }
}